// Round 11
// baseline (212.611 us; speedup 1.0000x reference)
//
#include <hip/hip_runtime.h>
#include <math.h>

#define H_    8
#define DH_   64
#define SPD   512
#define NSEQ  2048
#define BATCH 4
#define ROWS  8192
#define KDIM  513
#define INVK  10.0f
#define SQRTK 0.31622776601683794f
#define S2C   0.18033688011112043f   // SCALE * log2(e)
#define LOG2E 1.4426950408889634f
#define TKOFF 12.0f

using bf16x8 = __attribute__((ext_vector_type(8))) short;
using f32x4  = __attribute__((ext_vector_type(4))) float;
using f32x16 = __attribute__((ext_vector_type(16))) float;

static __device__ __forceinline__ short f2bf(float f){
  union { float f; unsigned u; } v; v.f = f;
  unsigned r = v.u + 0x7fffu + ((v.u >> 16) & 1u);
  return (short)(r >> 16);
}
static __device__ __forceinline__ float bf2f(short s){
  union { unsigned u; float f; } v; v.u = ((unsigned)(unsigned short)s) << 16;
  return v.f;
}
static __device__ __forceinline__ unsigned cvtpk(float lo, float hi){
  unsigned r; asm("v_cvt_pk_bf16_f32 %0, %1, %2" : "=v"(r) : "v"(lo), "v"(hi)); return r;
}
static __device__ __forceinline__ void plswapu(unsigned& a, unsigned& b){
  asm("v_permlane32_swap_b32 %0, %1" : "+v"(a), "+v"(b));
}
static __device__ __forceinline__ float exp2v(float x){
  float r; asm("v_exp_f32 %0, %1" : "=v"(r) : "v"(x)); return r;
}

#define GL16(gp, lp) __builtin_amdgcn_global_load_lds( \
    (const __attribute__((address_space(1))) void*)(gp), \
    (__attribute__((address_space(3))) void*)(lp), 16, 0, 0)

// ---------------- conversions (merged) ----------------
__global__ __launch_bounds__(256) void conv_kernel(const float* __restrict__ x,
                                                   const float* __restrict__ Wq,
                                                   const float* __restrict__ Wk,
                                                   const float* __restrict__ Wv,
                                                   const float* __restrict__ Wo,
                                                   short* __restrict__ xs,
                                                   short* __restrict__ WT){
  const int bid = blockIdx.x;
  if (bid < 8192){
    const int i2 = (bid * 256 + threadIdx.x) * 2;
    const int r = i2 >> 9, c = i2 & 511;
    const float a = x[(size_t)r * KDIM + 1 + c];
    const float b = x[(size_t)r * KDIM + 2 + c];
    const unsigned pk = (unsigned)(unsigned short)f2bf(a) |
                        ((unsigned)(unsigned short)f2bf(b) << 16);
    *(unsigned*)(xs + (size_t)r * SPD + c) = pk;
  } else {
    const int q = bid - 8192;
    const int wsel = q >> 10;
    const float* W = (wsel == 0) ? Wq : (wsel == 1) ? Wk : (wsel == 2) ? Wv : Wo;
    const int i = (q & 1023) * 256 + threadIdx.x;
    const int n = i >> 9, k = i & 511;
    WT[(size_t)wsel * SPD * SPD + i] = f2bf(W[(size_t)(k + 1) * SPD + n]);
  }
}

// ---------------- GEMM: C[M,512] = As[M,512] @ WT^T + t*W0 + bias ----------------
template<bool BF16OUT, int BM, bool FUSESSQ>
__global__ __launch_bounds__(256) void gemm_kernel(
    const short* __restrict__ A, const short* __restrict__ WTbase,
    int sel0, int sel1, int sel2,
    const float* __restrict__ bias0, const float* __restrict__ bias1,
    const float* __restrict__ bias2,
    const float* __restrict__ W00, const float* __restrict__ W01,
    const float* __restrict__ W02,
    const float* __restrict__ tvec, long tstride,
    float* __restrict__ ssqout,
    void* __restrict__ C0, void* __restrict__ C1, void* __restrict__ C2,
    int ldc, int coff)
{
  constexpr int NREP = (BM == 128) ? 4 : 2;
  const int z = blockIdx.z;
  const int sel = (z == 0) ? sel0 : (z == 1) ? sel1 : sel2;
  const short* BT = WTbase + (size_t)sel * SPD * SPD;
  const float* bias = (z == 0) ? bias0 : (z == 1) ? bias1 : bias2;
  const float* W0 = (z == 0) ? W00 : (z == 1) ? W01 : W02;
  void* C = (z == 0) ? C0 : (z == 1) ? C1 : C2;

  __shared__ short As[BM * 32];
  __shared__ short Bs[128 * 32];

  const int tid  = threadIdx.x;
  const int lane = tid & 63;
  const int wave = tid >> 6;
  const int row0 = blockIdx.x * BM;
  const int col0 = blockIdx.y * 128;
  const int wr = (BM == 128) ? (wave >> 1) * 64 : 0;
  const int wc = (BM == 128) ? (wave & 1) * 64 : wave * 32;
  const int rA  = lane & 15;
  const int kg2 = (lane >> 4) * 16;
  const int g4  = lane >> 4;

  f32x4 acc[4][NREP] = {};

  for (int kt = 0; kt < SPD / 32; ++kt){
    __syncthreads();
    #pragma unroll
    for (int p = 0; p < BM / 64; ++p){
      const int idx = p * 256 + tid;
      const int r = idx >> 2, c4 = idx & 3;
      const int gc = (c4 ^ ((r >> 1) & 3)) * 8;
      GL16(A + (size_t)(row0 + r) * SPD + kt * 32 + gc, (char*)As + idx * 16);
    }
    #pragma unroll
    for (int p = 0; p < 2; ++p){
      const int idx = p * 256 + tid;
      const int r = idx >> 2, c4 = idx & 3;
      const int gc = (c4 ^ ((r >> 1) & 3)) * 8;
      GL16(BT + (size_t)(col0 + r) * SPD + kt * 32 + gc, (char*)Bs + idx * 16);
    }
    asm volatile("s_waitcnt vmcnt(0)" ::: "memory");
    __syncthreads();
    bf16x8 af[4], bfr[NREP];
    #pragma unroll
    for (int m = 0; m < 4; ++m){
      const int r = wr + m * 16 + rA;
      af[m] = *(const bf16x8*)((const char*)As + ((r * 64 + kg2) ^ (((r >> 1) & 3) << 4)));
    }
    #pragma unroll
    for (int n = 0; n < NREP; ++n){
      const int r = wc + n * 16 + rA;
      bfr[n] = *(const bf16x8*)((const char*)Bs + ((r * 64 + kg2) ^ (((r >> 1) & 3) << 4)));
    }
    #pragma unroll
    for (int m = 0; m < 4; ++m)
      #pragma unroll
      for (int n = 0; n < NREP; ++n)
        acc[m][n] = __builtin_amdgcn_mfma_f32_16x16x32_bf16(af[m], bfr[n], acc[m][n], 0, 0, 0);
  }

  float trow[4][4];
  #pragma unroll
  for (int m = 0; m < 4; ++m)
    #pragma unroll
    for (int j = 0; j < 4; ++j)
      trow[m][j] = tvec[(size_t)(row0 + wr + m * 16 + g4 * 4 + j) * tstride];

  float rssq[4][4];
  #pragma unroll
  for (int m = 0; m < 4; ++m)
    #pragma unroll
    for (int j = 0; j < 4; ++j) rssq[m][j] = 0.f;

  #pragma unroll
  for (int m = 0; m < 4; ++m){
    const int row = row0 + wr + m * 16 + g4 * 4;
    #pragma unroll
    for (int n = 0; n < NREP; ++n){
      const int col = col0 + wc + n * 16 + rA;
      const float bv = bias[col];
      const float w0 = W0[col];
      #pragma unroll
      for (int j = 0; j < 4; ++j){
        const float v = acc[m][n][j] + trow[m][j] * w0 + bv;
        if (FUSESSQ) rssq[m][j] += v * v;
        if (BF16OUT) ((short*)C)[(size_t)(row + j) * SPD + col] = f2bf(v);
        else         ((float*)C)[(size_t)(row + j) * ldc + coff + col] = v;
      }
    }
  }
  if (FUSESSQ){
    #pragma unroll
    for (int m = 0; m < 4; ++m)
      #pragma unroll
      for (int j = 0; j < 4; ++j){
        float s = rssq[m][j];
        s += __shfl_xor(s, 1, 64);
        s += __shfl_xor(s, 2, 64);
        s += __shfl_xor(s, 4, 64);
        s += __shfl_xor(s, 8, 64);
        if (rA == 0) atomicAdd(&ssqout[row0 + wr + m * 16 + g4 * 4 + j], s);
      }
  }
}

// ---------------- post-QKV: wave-per-row, vectorized, barrier-free ----------------
__global__ __launch_bounds__(256) void postqkv_kernel(
    const short* __restrict__ qb, const short* __restrict__ kb,
    const short* __restrict__ vb, float* __restrict__ tq,
    unsigned* __restrict__ tkpk, short* __restrict__ vtT)
{
  const int tid = threadIdx.x;
  const int lane = tid & 63;
  const int wv = tid >> 6;
  const int row0 = blockIdx.x * 8 + wv * 2;
  const int b = blockIdx.x >> 8;

  #pragma unroll
  for (int i = 0; i < 2; ++i){
    const int row = row0 + i;
    const int n = row & (NSEQ - 1);
    {
      union { bf16x8 v; short e[8]; } u;
      u.v = *(const bf16x8*)(qb + (size_t)row * SPD + lane * 8);
      float s = 0.f;
      #pragma unroll
      for (int j = 0; j < 8; ++j){ const float f = bf2f(u.e[j]); s += f * f; }
      #pragma unroll
      for (int m = 1; m <= 32; m <<= 1) s += __shfl_xor(s, m, 64);
      if (lane == 0) tq[row] = sqrtf(INVK + s);
    }
    {
      union { bf16x8 v; short e[8]; } u;
      u.v = *(const bf16x8*)(kb + (size_t)row * SPD + lane * 8);
      float s = 0.f;
      #pragma unroll
      for (int j = 0; j < 8; ++j){ const float f = bf2f(u.e[j]); s += f * f; }
      #pragma unroll
      for (int m = 1; m <= 32; m <<= 1) s += __shfl_xor(s, m, 64);
      if (lane == 0){
        const float tkm = sqrtf(INVK + s) - TKOFF;
        const short bhi = f2bf(tkm);
        const short blo = f2bf(tkm - bf2f(bhi));
        tkpk[row] = (unsigned)(unsigned short)bhi | ((unsigned)(unsigned short)blo << 16);
      }
    }
    {
      union { bf16x8 v; short e[8]; } u;
      u.v = *(const bf16x8*)(vb + (size_t)row * SPD + lane * 8);
      float f[8]; float sh = 0.f;
      #pragma unroll
      for (int j = 0; j < 8; ++j){ f[j] = bf2f(u.e[j]); sh += f[j] * f[j]; }
      sh += __shfl_xor(sh, 1, 64);
      sh += __shfl_xor(sh, 2, 64);
      sh += __shfl_xor(sh, 4, 64);
      float tot = sh;
      tot += __shfl_xor(tot, 8, 64);
      tot += __shfl_xor(tot, 16, 64);
      tot += __shfl_xor(tot, 32, 64);
      const float tv = sqrtf(INVK + tot);
      const float av = fmaxf(SQRTK * tv, 1.0f + 1e-7f);
      const float theta = __logf(av + sqrtf(av * av - 1.0f));
      const float fac = theta * (1.0f / SQRTK);
      const float inv = fac / fmaxf(sqrtf(sh), 1e-9f);
      const int h = lane >> 3;
      const int d0 = (lane & 7) * 8;
      short* dst = vtT + ((size_t)((b * H_ + h) * DH_ + d0)) * NSEQ + n;
      #pragma unroll
      for (int j = 0; j < 8; ++j) dst[(size_t)j * NSEQ] = f2bf(inv * f[j]);
    }
  }
}

// ---------------- flash attention: KVBLK=128, MFMA time-term + MFMA l-sum ----------------
__global__ __launch_bounds__(256) void attn_kernel(
    const short* __restrict__ qb, const short* __restrict__ kb,
    const short* __restrict__ vtT, const float* __restrict__ tqg,
    const unsigned* __restrict__ tkpk, short* __restrict__ catb)
{
  int bid = blockIdx.x;
  bid = (bid & 7) * 64 + (bid >> 3);          // XCD-chunked swizzle (512 = 8*64)
  const int qt = bid & 15;
  const int bh = bid >> 4;
  const int b = bh >> 3, h = bh & 7;
  const int q0 = qt * 128;
  const int tid = threadIdx.x;
  const int lane = tid & 63;
  const int w = tid >> 6;
  const int l31 = lane & 31;
  const int hi = lane >> 5;

  __shared__ short Ks[2][128 * 64];   // [kv][d], 128B rows
  __shared__ short Vs[2][64 * 128];   // [d][kv], 256B rows
  __shared__ float lred[4][32];
  __shared__ unsigned tks[NSEQ];      // packed (hi,lo) bf16 of tk-12 (8 KB)

  const int qrow = q0 + w * 32 + l31;
  bf16x8 qf[4];
  {
    const short* qptr = qb + (size_t)(b * NSEQ + qrow) * SPD + h * DH_ + hi * 8;
    #pragma unroll
    for (int s = 0; s < 4; ++s){
      union { bf16x8 v; short e[8]; } u;
      u.v = *(const bf16x8*)(qptr + s * 16);
      #pragma unroll
      for (int j = 0; j < 8; ++j) u.e[j] = f2bf(bf2f(u.e[j]) * S2C);
      qf[s] = u.v;
    }
  }
  // aug Q slice: slots {0,1,2} = {Ahi, Alo, Ahi} of A = -S2C*tq   (hi half: zeros)
  bf16x8 qf4;
  {
    const float a = -S2C * tqg[b * NSEQ + qrow];
    const short ahi = f2bf(a);
    const short alo = f2bf(a - bf2f(ahi));
    union { unsigned u[4]; bf16x8 v; } q4;
    q4.u[0] = hi ? 0u : ((unsigned)(unsigned short)ahi | ((unsigned)(unsigned short)alo << 16));
    q4.u[1] = hi ? 0u : (unsigned)(unsigned short)ahi;
    q4.u[2] = 0; q4.u[3] = 0;
    qf4 = q4.v;
  }
  // ones B-operand (col 0 = ones) for the l-sum MFMA
  bf16x8 onesB;
  {
    const unsigned val = (l31 == 0) ? 0x3f803f80u : 0u;
    union { unsigned u[4]; bf16x8 v; } ob;
    ob.u[0] = val; ob.u[1] = val; ob.u[2] = val; ob.u[3] = val;
    onesB = ob.v;
  }

  {
    const unsigned* tsrc = tkpk + b * NSEQ + tid * 8;
    *(uint4*)&tks[tid * 8]     = *(const uint4*)tsrc;
    *(uint4*)&tks[tid * 8 + 4] = *(const uint4*)(tsrc + 4);
  }

  // hoisted per-lane swizzled LDS byte offsets (loop-invariant)
  int koffK[4][4];   // K: rows kv (128B, swz (row&7)<<4)
  #pragma unroll
  for (int f = 0; f < 4; ++f)
    #pragma unroll
    for (int s = 0; s < 4; ++s)
      koffK[f][s] = (f * 32 + l31) * 128 + ((s * 32 + hi * 16) ^ ((l31 & 7) << 4));
  int koffV[2][8];   // V: rows d (256B, swz (row&15)<<4)
  #pragma unroll
  for (int db = 0; db < 2; ++db)
    #pragma unroll
    for (int ks = 0; ks < 8; ++ks)
      koffV[db][ks] = (db * 32 + l31) * 256 + ((ks * 32 + hi * 16) ^ ((l31 & 15) << 4));

  // staging geometry
  const int rK = tid >> 3;                 // 0..31, K rows rK + 32g
  const int cK = (tid & 7) * 16;           // byte col in 128B row
  const int ccK = cK ^ ((rK & 7) << 4);
  const int rV = tid >> 4;                 // 0..15, V rows rV + 16g
  const int cV = (tid & 15) * 16;          // byte col in 256B row
  const int ccV = cV ^ ((rV & 15) << 4);
  const short* kbase = kb + (size_t)(b * NSEQ) * SPD + h * DH_;
  const short* vbase = vtT + (size_t)(bh * DH_) * NSEQ;

  uint4 kA[4], vA[4], kB[4], vB[4];

#define LOADA(m0) do{ _Pragma("unroll") for (int g = 0; g < 4; ++g){ \
    kA[g] = *(const uint4*)(kbase + (size_t)((m0) + g * 32 + rK) * SPD + (cK >> 1)); \
    vA[g] = *(const uint4*)(vbase + (size_t)(g * 16 + rV) * NSEQ + (m0) + (cV >> 1)); } }while(0)
#define LOADB(m0) do{ _Pragma("unroll") for (int g = 0; g < 4; ++g){ \
    kB[g] = *(const uint4*)(kbase + (size_t)((m0) + g * 32 + rK) * SPD + (cK >> 1)); \
    vB[g] = *(const uint4*)(vbase + (size_t)(g * 16 + rV) * NSEQ + (m0) + (cV >> 1)); } }while(0)
#define WRITEA(buf) do{ _Pragma("unroll") for (int g = 0; g < 4; ++g){ \
    *(uint4*)((char*)Ks[buf] + (g * 32 + rK) * 128 + ccK) = kA[g]; \
    *(uint4*)((char*)Vs[buf] + (g * 16 + rV) * 256 + ccV) = vA[g]; } }while(0)
#define WRITEB(buf) do{ _Pragma("unroll") for (int g = 0; g < 4; ++g){ \
    *(uint4*)((char*)Ks[buf] + (g * 32 + rK) * 128 + ccK) = kB[g]; \
    *(uint4*)((char*)Vs[buf] + (g * 16 + rV) * 256 + ccV) = vB[g]; } }while(0)
#define BARRIER() asm volatile("s_waitcnt lgkmcnt(0)\n\ts_barrier" ::: "memory")
#define WAITV8()  asm volatile("s_waitcnt vmcnt(8)" ::: "memory")
#define WAITV0()  asm volatile("s_waitcnt vmcnt(0)" ::: "memory")

  f32x16 o[2] = {};
  f32x16 lacc = {};
  const f32x16 z16 = {};

  auto KAUG = [&](unsigned pk)->bf16x8{
    union { unsigned u[4]; bf16x8 v; } ka;
    ka.u[0] = hi ? 0u : ((pk & 0xFFFFu) | (pk << 16));
    ka.u[1] = hi ? 0u : (pk >> 16);
    ka.u[2] = 0; ka.u[3] = 0;
    return ka.v;
  };

  auto COMPUTE = [&](const char* Kc, const char* Vc, int m0){
    unsigned pk[4];
    #pragma unroll
    for (int f = 0; f < 4; ++f) pk[f] = tks[m0 + f * 32 + l31];

    f32x16 sacc[4];
    __builtin_amdgcn_s_setprio(1);
    #pragma unroll
    for (int f = 0; f < 4; ++f){
      {
        const bf16x8 kf = *(const bf16x8*)(Kc + koffK[f][0]);
        sacc[f] = __builtin_amdgcn_mfma_f32_32x32x16_bf16(kf, qf[0], z16, 0, 0, 0);
      }
      #pragma unroll
      for (int s = 1; s < 4; ++s){
        const bf16x8 kf = *(const bf16x8*)(Kc + koffK[f][s]);
        sacc[f] = __builtin_amdgcn_mfma_f32_32x32x16_bf16(kf, qf[s], sacc[f], 0, 0, 0);
      }
      sacc[f] = __builtin_amdgcn_mfma_f32_32x32x16_bf16(KAUG(pk[f]), qf4, sacc[f], 0, 0, 0);
    }
    __builtin_amdgcn_s_setprio(0);

    // P = exp2(score) directly — no max needed (score bounded in f32)
    #pragma unroll
    for (int f = 0; f < 4; ++f)
      #pragma unroll
      for (int e = 0; e < 16; ++e)
        sacc[f][e] = exp2v(sacc[f][e]);

    // P -> bf16 A-operand fragments via cvt_pk + permlane32_swap (T12)
    bf16x8 pa[8];
    #pragma unroll
    for (int f = 0; f < 4; ++f)
      #pragma unroll
      for (int g16 = 0; g16 < 2; ++g16){
        const int bse = g16 * 8;
        unsigned A0 = cvtpk(sacc[f][bse + 0], sacc[f][bse + 1]);
        unsigned A1 = cvtpk(sacc[f][bse + 2], sacc[f][bse + 3]);
        unsigned B0 = cvtpk(sacc[f][bse + 4], sacc[f][bse + 5]);
        unsigned B1 = cvtpk(sacc[f][bse + 6], sacc[f][bse + 7]);
        plswapu(A0, B0);
        plswapu(A1, B1);
        union { unsigned u[4]; bf16x8 v; } pu;
        pu.u[0] = A0; pu.u[1] = A1; pu.u[2] = B0; pu.u[3] = B1;
        pa[f * 2 + g16] = pu.v;
      }

    // O += P · V ;  l += P · 1
    __builtin_amdgcn_s_setprio(1);
    #pragma unroll
    for (int db = 0; db < 2; ++db)
      #pragma unroll
      for (int ks = 0; ks < 8; ++ks){
        const bf16x8 vf = *(const bf16x8*)(Vc + koffV[db][ks]);
        o[db] = __builtin_amdgcn_mfma_f32_32x32x16_bf16(pa[ks], vf, o[db], 0, 0, 0);
      }
    #pragma unroll
    for (int ks = 0; ks < 8; ++ks)
      lacc = __builtin_amdgcn_mfma_f32_32x32x16_bf16(pa[ks], onesB, lacc, 0, 0, 0);
    __builtin_amdgcn_s_setprio(0);
  };

  LOADA(0);
  WAITV0();
  WRITEA(0);
  __syncthreads();
  LOADB(128);

  const int NT = NSEQ / 128;   // 16 tiles
  #pragma unroll 1
  for (int t = 0; t < NT; t += 2){
    const int m0 = t * 128;
    if (t + 2 < NT) LOADA(m0 + 256);
    COMPUTE((const char*)Ks[0], (const char*)Vs[0], m0);
    if (t + 2 < NT) WAITV8(); else WAITV0();
    WRITEB(1);
    BARRIER();
    if (t + 3 < NT) LOADB(m0 + 384);
    COMPUTE((const char*)Ks[1], (const char*)Vs[1], m0 + 128);
    if (t + 2 < NT){
      if (t + 3 < NT) WAITV8(); else WAITV0();
      WRITEA(0);
    }
    BARRIER();
  }

  // epilogue: l broadcast, normalize, expmap0 spatial part
  if (l31 == 0){
    #pragma unroll
    for (int e = 0; e < 16; ++e)
      lred[w][(e & 3) + 8 * (e >> 2) + 4 * hi] = lacc[e];
  }
  asm volatile("s_waitcnt lgkmcnt(0)" ::: "memory");
  f32x4 lv[4];
  #pragma unroll
  for (int g = 0; g < 4; ++g) lv[g] = *(const f32x4*)&lred[w][8 * g + 4 * hi];

  const size_t obase = (size_t)(b * NSEQ + q0 + w * 32) * SPD + h * DH_ + l31;
  #pragma unroll
  for (int e = 0; e < 16; ++e){
    const float linv = __builtin_amdgcn_rcpf(lv[e >> 2][e & 3]);
    const float ov0 = o[0][e] * linv;
    const float ov1 = o[1][e] * linv;
    float ss = ov0 * ov0 + ov1 * ov1;
    #pragma unroll
    for (int off = 16; off; off >>= 1) ss += __shfl_xor(ss, off, 64);
    const float nrm = sqrtf(ss);
    const float e2 = exp2f(SQRTK * nrm * LOG2E);
    const float einv = __builtin_amdgcn_rcpf(e2);
    const float fac = (e2 - einv) * 0.5f * __builtin_amdgcn_rcpf(SQRTK * fmaxf(nrm, 1e-9f));
    const int crow = (e & 3) + 8 * (e >> 2) + 4 * hi;
    catb[obase + (size_t)crow * SPD]      = f2bf(fac * ov0);
    catb[obase + (size_t)crow * SPD + 32] = f2bf(fac * ov1);
  }
#undef LOADA
#undef LOADB
#undef WRITEA
#undef WRITEB
#undef BARRIER
#undef WAITV8
#undef WAITV0
}

// ---------------- t' per row (wave-per-row, vectorized) ----------------
__global__ __launch_bounds__(256) void tp_kernel(const short* __restrict__ catb,
                                                 float* __restrict__ tps){
  const int lane = threadIdx.x & 63;
  const int row = blockIdx.x * 4 + (threadIdx.x >> 6);
  union { bf16x8 v; short e[8]; } u;
  u.v = *(const bf16x8*)(catb + (size_t)row * SPD + lane * 8);
  float s = 0.f;
  #pragma unroll
  for (int j = 0; j < 8; ++j){ const float f = bf2f(u.e[j]); s += f * f; }
  #pragma unroll
  for (int m = 1; m <= 32; m <<= 1) s += __shfl_xor(s, m, 64);
  if (lane == 0) tps[row] = sqrtf(fmaxf(INVK + s, 1e-9f));
}

// ---------------- final t_o column from accumulated ssq ----------------
__global__ __launch_bounds__(256) void fin2_kernel(float* __restrict__ out,
                                                   const float* __restrict__ tos){
  const int r = blockIdx.x * 256 + threadIdx.x;
  out[(size_t)r * KDIM] = sqrtf(fmaxf(INVK + tos[r], 1e-9f));
}

extern "C" void kernel_launch(void* const* d_in, const int* in_sizes, int n_in,
                              void* d_out, int out_size, void* d_ws, size_t ws_size,
                              hipStream_t stream)
{
  (void)in_sizes; (void)n_in; (void)out_size; (void)ws_size;
  const float* x  = (const float*)d_in[0];
  const float* Wq = (const float*)d_in[1];
  const float* bq = (const float*)d_in[2];
  const float* Wk = (const float*)d_in[3];
  const float* bk = (const float*)d_in[4];
  const float* Wv = (const float*)d_in[5];
  const float* bv = (const float*)d_in[6];
  const float* Wo = (const float*)d_in[7];
  const float* bo = (const float*)d_in[8];
  float* out = (float*)d_out;

  char* p = (char*)d_ws;
  short* xs   = (short*)p; p += (size_t)ROWS * SPD * 2;
  short* WT   = (short*)p; p += (size_t)4 * SPD * SPD * 2;
  short* qb   = (short*)p; p += (size_t)ROWS * SPD * 2;
  short* kb   = (short*)p; p += (size_t)ROWS * SPD * 2;
  short* vb   = (short*)p; p += (size_t)ROWS * SPD * 2;
  short* vtT  = (short*)p; p += (size_t)ROWS * SPD * 2;
  float* tq   = (float*)p; p += (size_t)ROWS * 4;
  unsigned* tkpk = (unsigned*)p; p += (size_t)ROWS * 4;
  short* catb = (short*)p; p += (size_t)ROWS * SPD * 2;
  float* tps  = (float*)p; p += (size_t)ROWS * 4;
  float* tos  = (float*)p; p += (size_t)ROWS * 4;

  hipMemsetAsync(tos, 0, (size_t)ROWS * 4, stream);
  conv_kernel<<<8192 + 4096, 256, 0, stream>>>(x, Wq, Wk, Wv, Wo, xs, WT);
  gemm_kernel<true, 128, false><<<dim3(64, 4, 3), 256, 0, stream>>>(
      xs, WT, 0, 1, 2, bq, bk, bv, Wq, Wk, Wv, x, (long)KDIM, nullptr,
      qb, kb, vb, SPD, 0);
  postqkv_kernel<<<1024, 256, 0, stream>>>(qb, kb, vb, tq, tkpk, vtT);
  attn_kernel<<<512, 256, 0, stream>>>(qb, kb, vtT, tq, tkpk, catb);
  tp_kernel<<<ROWS / 4, 256, 0, stream>>>(catb, tps);
  gemm_kernel<false, 64, true><<<dim3(128, 4, 1), 256, 0, stream>>>(
      catb, WT, 3, 3, 3, bo, bo, bo, Wo, Wo, Wo, tps, 1L, tos,
      out, out, out, KDIM, 1);
  fin2_kernel<<<ROWS / 256, 256, 0, stream>>>(out, tos);
}

// Round 12
// 142.093 us; speedup vs baseline: 1.4963x; 1.4963x over previous
//
#include <hip/hip_runtime.h>
#include <math.h>

#define H_    8
#define DH_   64
#define SPD   512
#define NSEQ  2048
#define BATCH 4
#define ROWS  8192
#define KDIM  513
#define INVK  10.0f
#define SQRTK 0.31622776601683794f
#define S2C   0.18033688011112043f   // SCALE * log2(e)
#define LOG2E 1.4426950408889634f
#define TKOFF 12.0f

using bf16x8 = __attribute__((ext_vector_type(8))) short;
using f32x4  = __attribute__((ext_vector_type(4))) float;
using f32x16 = __attribute__((ext_vector_type(16))) float;

static __device__ __forceinline__ short f2bf(float f){
  union { float f; unsigned u; } v; v.f = f;
  unsigned r = v.u + 0x7fffu + ((v.u >> 16) & 1u);
  return (short)(r >> 16);
}
static __device__ __forceinline__ float bf2f(short s){
  union { unsigned u; float f; } v; v.u = ((unsigned)(unsigned short)s) << 16;
  return v.f;
}
static __device__ __forceinline__ unsigned cvtpk(float lo, float hi){
  unsigned r; asm("v_cvt_pk_bf16_f32 %0, %1, %2" : "=v"(r) : "v"(lo), "v"(hi)); return r;
}
static __device__ __forceinline__ void plswapu(unsigned& a, unsigned& b){
  asm("v_permlane32_swap_b32 %0, %1" : "+v"(a), "+v"(b));
}
static __device__ __forceinline__ float exp2v(float x){
  float r; asm("v_exp_f32 %0, %1" : "=v"(r) : "v"(x)); return r;
}

#define GL16(gp, lp) __builtin_amdgcn_global_load_lds( \
    (const __attribute__((address_space(1))) void*)(gp), \
    (__attribute__((address_space(3))) void*)(lp), 16, 0, 0)

// ---------------- conversions (merged, one launch) ----------------
__global__ __launch_bounds__(256) void conv_kernel(const float* __restrict__ x,
                                                   const float* __restrict__ Wq,
                                                   const float* __restrict__ Wk,
                                                   const float* __restrict__ Wv,
                                                   const float* __restrict__ Wo,
                                                   short* __restrict__ xs,
                                                   short* __restrict__ WT){
  const int bid = blockIdx.x;
  if (bid < 8192){
    const int i2 = (bid * 256 + threadIdx.x) * 2;
    const int r = i2 >> 9, c = i2 & 511;
    const float a = x[(size_t)r * KDIM + 1 + c];
    const float b = x[(size_t)r * KDIM + 2 + c];
    const unsigned pk = (unsigned)(unsigned short)f2bf(a) |
                        ((unsigned)(unsigned short)f2bf(b) << 16);
    *(unsigned*)(xs + (size_t)r * SPD + c) = pk;
  } else {
    const int q = bid - 8192;
    const int wsel = q >> 10;
    const float* W = (wsel == 0) ? Wq : (wsel == 1) ? Wk : (wsel == 2) ? Wv : Wo;
    const int i = (q & 1023) * 256 + threadIdx.x;
    const int n = i >> 9, k = i & 511;
    WT[(size_t)wsel * SPD * SPD + i] = f2bf(W[(size_t)(k + 1) * SPD + n]);
  }
}

// ---------------- GEMM: C[M,512] = As[M,512] @ WT^T + t*W0 + bias  (BK=64) ----------------
template<bool BF16OUT, int BM>
__global__ __launch_bounds__(256) void gemm_kernel(
    const short* __restrict__ A, const short* __restrict__ WTbase,
    int sel0, int sel1, int sel2,
    const float* __restrict__ bias0, const float* __restrict__ bias1,
    const float* __restrict__ bias2,
    const float* __restrict__ W00, const float* __restrict__ W01,
    const float* __restrict__ W02,
    const float* __restrict__ tvec, long tstride,
    void* __restrict__ C0, void* __restrict__ C1, void* __restrict__ C2,
    int ldc, int coff)
{
  constexpr int NREP = (BM == 128) ? 4 : 2;
  const int z = blockIdx.z;
  const int sel = (z == 0) ? sel0 : (z == 1) ? sel1 : sel2;
  const short* BT = WTbase + (size_t)sel * SPD * SPD;
  const float* bias = (z == 0) ? bias0 : (z == 1) ? bias1 : bias2;
  const float* W0 = (z == 0) ? W00 : (z == 1) ? W01 : W02;
  void* C = (z == 0) ? C0 : (z == 1) ? C1 : C2;

  __shared__ short As[BM * 64];
  __shared__ short Bs[128 * 64];

  const int tid  = threadIdx.x;
  const int lane = tid & 63;
  const int wave = tid >> 6;
  const int row0 = blockIdx.x * BM;
  const int col0 = blockIdx.y * 128;
  const int wr = (BM == 128) ? (wave >> 1) * 64 : 0;
  const int wc = (BM == 128) ? (wave & 1) * 64 : wave * 32;
  const int rA  = lane & 15;
  const int g4  = lane >> 4;

  f32x4 acc[4][NREP] = {};

  for (int kt = 0; kt < SPD / 64; ++kt){   // 8 K-rounds
    __syncthreads();
    // stage: granule(16B) index idx; row r = idx>>3, lds-granule c8 = idx&7;
    // source granule = c8 ^ (r&7)  (inverse-swizzled source, linear LDS dest)
    #pragma unroll
    for (int p = 0; p < BM / 32; ++p){
      const int idx = p * 256 + tid;
      const int r = idx >> 3, c8 = idx & 7;
      const int gc = (c8 ^ (r & 7)) * 8;
      GL16(A + (size_t)(row0 + r) * SPD + kt * 64 + gc, (char*)As + idx * 16);
    }
    #pragma unroll
    for (int p = 0; p < 4; ++p){
      const int idx = p * 256 + tid;
      const int r = idx >> 3, c8 = idx & 7;
      const int gc = (c8 ^ (r & 7)) * 8;
      GL16(BT + (size_t)(col0 + r) * SPD + kt * 64 + gc, (char*)Bs + idx * 16);
    }
    asm volatile("s_waitcnt vmcnt(0)" ::: "memory");
    __syncthreads();
    // read: global granule G = ks*4+g4 lives at LDS granule G^(r&7)
    bf16x8 af[4][2], bfr[NREP][2];
    #pragma unroll
    for (int m = 0; m < 4; ++m){
      const int r = wr + m * 16 + rA;
      #pragma unroll
      for (int ks = 0; ks < 2; ++ks){
        const int g = (ks * 4 + g4) ^ (r & 7);
        af[m][ks] = *(const bf16x8*)((const char*)As + r * 128 + g * 16);
      }
    }
    #pragma unroll
    for (int n = 0; n < NREP; ++n){
      const int r = wc + n * 16 + rA;
      #pragma unroll
      for (int ks = 0; ks < 2; ++ks){
        const int g = (ks * 4 + g4) ^ (r & 7);
        bfr[n][ks] = *(const bf16x8*)((const char*)Bs + r * 128 + g * 16);
      }
    }
    #pragma unroll
    for (int ks = 0; ks < 2; ++ks)
      #pragma unroll
      for (int m = 0; m < 4; ++m)
        #pragma unroll
        for (int n = 0; n < NREP; ++n)
          acc[m][n] = __builtin_amdgcn_mfma_f32_16x16x32_bf16(af[m][ks], bfr[n][ks], acc[m][n], 0, 0, 0);
  }

  float trow[4][4];
  #pragma unroll
  for (int m = 0; m < 4; ++m)
    #pragma unroll
    for (int j = 0; j < 4; ++j)
      trow[m][j] = tvec[(size_t)(row0 + wr + m * 16 + g4 * 4 + j) * tstride];

  #pragma unroll
  for (int m = 0; m < 4; ++m){
    const int row = row0 + wr + m * 16 + g4 * 4;
    #pragma unroll
    for (int n = 0; n < NREP; ++n){
      const int col = col0 + wc + n * 16 + rA;
      const float bv = bias[col];
      const float w0 = W0[col];
      #pragma unroll
      for (int j = 0; j < 4; ++j){
        const float v = acc[m][n][j] + trow[m][j] * w0 + bv;
        if (BF16OUT) ((short*)C)[(size_t)(row + j) * SPD + col] = f2bf(v);
        else         ((float*)C)[(size_t)(row + j) * ldc + coff + col] = v;
      }
    }
  }
}

// ---------------- post-QKV: wave-per-row, vectorized, barrier-free ----------------
__global__ __launch_bounds__(256) void postqkv_kernel(
    const short* __restrict__ qb, const short* __restrict__ kb,
    const short* __restrict__ vb, float* __restrict__ tq,
    unsigned* __restrict__ tkpk, short* __restrict__ vtT)
{
  const int tid = threadIdx.x;
  const int lane = tid & 63;
  const int wv = tid >> 6;
  const int row0 = blockIdx.x * 8 + wv * 2;
  const int b = blockIdx.x >> 8;

  #pragma unroll
  for (int i = 0; i < 2; ++i){
    const int row = row0 + i;
    const int n = row & (NSEQ - 1);
    {
      union { bf16x8 v; short e[8]; } u;
      u.v = *(const bf16x8*)(qb + (size_t)row * SPD + lane * 8);
      float s = 0.f;
      #pragma unroll
      for (int j = 0; j < 8; ++j){ const float f = bf2f(u.e[j]); s += f * f; }
      #pragma unroll
      for (int m = 1; m <= 32; m <<= 1) s += __shfl_xor(s, m, 64);
      if (lane == 0) tq[row] = sqrtf(INVK + s);
    }
    {
      union { bf16x8 v; short e[8]; } u;
      u.v = *(const bf16x8*)(kb + (size_t)row * SPD + lane * 8);
      float s = 0.f;
      #pragma unroll
      for (int j = 0; j < 8; ++j){ const float f = bf2f(u.e[j]); s += f * f; }
      #pragma unroll
      for (int m = 1; m <= 32; m <<= 1) s += __shfl_xor(s, m, 64);
      if (lane == 0){
        const float tkm = sqrtf(INVK + s) - TKOFF;
        const short bhi = f2bf(tkm);
        const short blo = f2bf(tkm - bf2f(bhi));
        tkpk[row] = (unsigned)(unsigned short)bhi | ((unsigned)(unsigned short)blo << 16);
      }
    }
    {
      union { bf16x8 v; short e[8]; } u;
      u.v = *(const bf16x8*)(vb + (size_t)row * SPD + lane * 8);
      float f[8]; float sh = 0.f;
      #pragma unroll
      for (int j = 0; j < 8; ++j){ f[j] = bf2f(u.e[j]); sh += f[j] * f[j]; }
      sh += __shfl_xor(sh, 1, 64);
      sh += __shfl_xor(sh, 2, 64);
      sh += __shfl_xor(sh, 4, 64);
      float tot = sh;
      tot += __shfl_xor(tot, 8, 64);
      tot += __shfl_xor(tot, 16, 64);
      tot += __shfl_xor(tot, 32, 64);
      const float tv = sqrtf(INVK + tot);
      const float av = fmaxf(SQRTK * tv, 1.0f + 1e-7f);
      const float theta = __logf(av + sqrtf(av * av - 1.0f));
      const float fac = theta * (1.0f / SQRTK);
      const float inv = fac / fmaxf(sqrtf(sh), 1e-9f);
      const int h = lane >> 3;
      const int d0 = (lane & 7) * 8;
      short* dst = vtT + ((size_t)((b * H_ + h) * DH_ + d0)) * NSEQ + n;
      #pragma unroll
      for (int j = 0; j < 8; ++j) dst[(size_t)j * NSEQ] = f2bf(inv * f[j]);
    }
  }
}

// ---------------- flash attention (round-9 body): MFMA time-term + MFMA l-sum ----------------
__global__ __launch_bounds__(256) void attn_kernel(
    const short* __restrict__ qb, const short* __restrict__ kb,
    const short* __restrict__ vtT, const float* __restrict__ tqg,
    const unsigned* __restrict__ tkpk, short* __restrict__ catb)
{
  int bid = blockIdx.x;
  bid = (bid & 7) * 64 + (bid >> 3);          // XCD-chunked swizzle (512 = 8*64)
  const int qt = bid & 15;
  const int bh = bid >> 4;
  const int b = bh >> 3, h = bh & 7;
  const int q0 = qt * 128;
  const int tid = threadIdx.x;
  const int lane = tid & 63;
  const int w = tid >> 6;
  const int l31 = lane & 31;
  const int hi = lane >> 5;
  const int rsw = (l31 & 7) << 4;

  __shared__ short Ks[2][64 * 64];
  __shared__ short Vs[2][64 * 64];   // V^T tile: rows d, cols kv
  __shared__ float lred[4][32];
  __shared__ unsigned tks[NSEQ];     // packed (hi,lo) bf16 of tk-12 (8 KB)

  const int qrow = q0 + w * 32 + l31;
  bf16x8 qf[4];
  {
    const short* qptr = qb + (size_t)(b * NSEQ + qrow) * SPD + h * DH_ + hi * 8;
    #pragma unroll
    for (int s = 0; s < 4; ++s){
      union { bf16x8 v; short e[8]; } u;
      u.v = *(const bf16x8*)(qptr + s * 16);
      #pragma unroll
      for (int j = 0; j < 8; ++j) u.e[j] = f2bf(bf2f(u.e[j]) * S2C);
      qf[s] = u.v;
    }
  }
  // aug Q slice: slots {0,1,2} = {Ahi, Alo, Ahi} of A = -S2C*tq   (hi half: zeros)
  bf16x8 qf4;
  {
    const float a = -S2C * tqg[b * NSEQ + qrow];
    const short ahi = f2bf(a);
    const short alo = f2bf(a - bf2f(ahi));
    union { unsigned u[4]; bf16x8 v; } q4;
    q4.u[0] = hi ? 0u : ((unsigned)(unsigned short)ahi | ((unsigned)(unsigned short)alo << 16));
    q4.u[1] = hi ? 0u : (unsigned)(unsigned short)ahi;
    q4.u[2] = 0; q4.u[3] = 0;
    qf4 = q4.v;
  }
  // ones B-operand (col 0 = ones) for the l-sum MFMA
  bf16x8 onesB;
  {
    const unsigned val = (l31 == 0) ? 0x3f803f80u : 0u;
    union { unsigned u[4]; bf16x8 v; } ob;
    ob.u[0] = val; ob.u[1] = val; ob.u[2] = val; ob.u[3] = val;
    onesB = ob.v;
  }

  {
    const unsigned* tsrc = tkpk + b * NSEQ + tid * 8;
    *(uint4*)&tks[tid * 8]     = *(const uint4*)tsrc;
    *(uint4*)&tks[tid * 8 + 4] = *(const uint4*)(tsrc + 4);
  }

  const int rB = tid >> 3;
  const int c0 = (tid & 7) * 16;
  const int cc = c0 ^ ((rB & 7) << 4);
  const short* kbase = kb + (size_t)(b * NSEQ) * SPD + h * DH_;
  const short* vbase = vtT + (size_t)(bh * DH_) * NSEQ;

  uint4 kA0, kA1, vA0, vA1;
  uint4 kB0, kB1, vB0, vB1;

#define LOADA(m0) do{ \
    kA0 = *(const uint4*)(kbase + (size_t)((m0) + rB) * SPD + (c0 >> 1)); \
    kA1 = *(const uint4*)(kbase + (size_t)((m0) + 32 + rB) * SPD + (c0 >> 1)); \
    vA0 = *(const uint4*)(vbase + (size_t)rB * NSEQ + (m0) + (c0 >> 1)); \
    vA1 = *(const uint4*)(vbase + (size_t)(32 + rB) * NSEQ + (m0) + (c0 >> 1)); }while(0)
#define LOADB(m0) do{ \
    kB0 = *(const uint4*)(kbase + (size_t)((m0) + rB) * SPD + (c0 >> 1)); \
    kB1 = *(const uint4*)(kbase + (size_t)((m0) + 32 + rB) * SPD + (c0 >> 1)); \
    vB0 = *(const uint4*)(vbase + (size_t)rB * NSEQ + (m0) + (c0 >> 1)); \
    vB1 = *(const uint4*)(vbase + (size_t)(32 + rB) * NSEQ + (m0) + (c0 >> 1)); }while(0)
#define WRITEA(buf) do{ \
    *(uint4*)((char*)Ks[buf] + rB * 128 + cc) = kA0; \
    *(uint4*)((char*)Ks[buf] + (32 + rB) * 128 + cc) = kA1; \
    *(uint4*)((char*)Vs[buf] + rB * 128 + cc) = vA0; \
    *(uint4*)((char*)Vs[buf] + (32 + rB) * 128 + cc) = vA1; }while(0)
#define WRITEB(buf) do{ \
    *(uint4*)((char*)Ks[buf] + rB * 128 + cc) = kB0; \
    *(uint4*)((char*)Ks[buf] + (32 + rB) * 128 + cc) = kB1; \
    *(uint4*)((char*)Vs[buf] + rB * 128 + cc) = vB0; \
    *(uint4*)((char*)Vs[buf] + (32 + rB) * 128 + cc) = vB1; }while(0)
#define BARRIER() asm volatile("s_waitcnt lgkmcnt(0)\n\ts_barrier" ::: "memory")
#define WAITV4()  asm volatile("s_waitcnt vmcnt(4)" ::: "memory")
#define WAITV0()  asm volatile("s_waitcnt vmcnt(0)" ::: "memory")

  f32x16 o[2] = {};
  f32x16 lacc = {};

  auto KAUG = [&](unsigned pk)->bf16x8{
    union { unsigned u[4]; bf16x8 v; } ka;
    ka.u[0] = hi ? 0u : ((pk & 0xFFFFu) | (pk << 16));
    ka.u[1] = hi ? 0u : (pk >> 16);
    ka.u[2] = 0; ka.u[3] = 0;
    return ka.v;
  };

  auto COMPUTE = [&](const char* Kc, const char* Vc, int m0){
    const unsigned pk0 = tks[m0 + l31];
    const unsigned pk1 = tks[m0 + 32 + l31];

    f32x16 sacc[2] = {};
    __builtin_amdgcn_s_setprio(1);
    #pragma unroll
    for (int f = 0; f < 2; ++f){
      const int rowb = (f * 32 + l31) * 128;
      #pragma unroll
      for (int s = 0; s < 4; ++s){
        const bf16x8 kf = *(const bf16x8*)(Kc + rowb + ((s * 32 + hi * 16) ^ rsw));
        sacc[f] = __builtin_amdgcn_mfma_f32_32x32x16_bf16(kf, qf[s], sacc[f], 0, 0, 0);
      }
    }
    sacc[0] = __builtin_amdgcn_mfma_f32_32x32x16_bf16(KAUG(pk0), qf4, sacc[0], 0, 0, 0);
    sacc[1] = __builtin_amdgcn_mfma_f32_32x32x16_bf16(KAUG(pk1), qf4, sacc[1], 0, 0, 0);
    __builtin_amdgcn_s_setprio(0);

    // P = exp2(score) directly — no max needed (score bounded in f32)
    #pragma unroll
    for (int f = 0; f < 2; ++f)
      #pragma unroll
      for (int e = 0; e < 16; ++e)
        sacc[f][e] = exp2v(sacc[f][e]);

    // P -> bf16 A-operand fragments via cvt_pk + permlane32_swap (T12)
    bf16x8 pa[4];
    #pragma unroll
    for (int f = 0; f < 2; ++f)
      #pragma unroll
      for (int g16 = 0; g16 < 2; ++g16){
        const int bse = g16 * 8;
        unsigned A0 = cvtpk(sacc[f][bse + 0], sacc[f][bse + 1]);
        unsigned A1 = cvtpk(sacc[f][bse + 2], sacc[f][bse + 3]);
        unsigned B0 = cvtpk(sacc[f][bse + 4], sacc[f][bse + 5]);
        unsigned B1 = cvtpk(sacc[f][bse + 6], sacc[f][bse + 7]);
        plswapu(A0, B0);
        plswapu(A1, B1);
        union { unsigned u[4]; bf16x8 v; } pu;
        pu.u[0] = A0; pu.u[1] = A1; pu.u[2] = B0; pu.u[3] = B1;
        pa[f * 2 + g16] = pu.v;
      }

    // O += P · V ;  l += P · 1
    __builtin_amdgcn_s_setprio(1);
    #pragma unroll
    for (int db = 0; db < 2; ++db){
      const int rowb = (db * 32 + l31) * 128;
      #pragma unroll
      for (int ks = 0; ks < 4; ++ks){
        const bf16x8 vf = *(const bf16x8*)(Vc + rowb + ((ks * 32 + hi * 16) ^ rsw));
        o[db] = __builtin_amdgcn_mfma_f32_32x32x16_bf16(pa[ks], vf, o[db], 0, 0, 0);
      }
    }
    #pragma unroll
    for (int ks = 0; ks < 4; ++ks)
      lacc = __builtin_amdgcn_mfma_f32_32x32x16_bf16(pa[ks], onesB, lacc, 0, 0, 0);
    __builtin_amdgcn_s_setprio(0);
  };

  LOADA(0);
  WAITV0();
  WRITEA(0);
  __syncthreads();
  LOADB(64);

  const int NT = NSEQ / 64;
  #pragma unroll 1
  for (int t = 0; t < NT; t += 2){
    const int m0 = t * 64;
    if (t + 2 < NT) LOADA(m0 + 128);
    COMPUTE((const char*)Ks[0], (const char*)Vs[0], m0);
    if (t + 2 < NT) WAITV4(); else WAITV0();
    WRITEB(1);
    BARRIER();
    if (t + 3 < NT) LOADB(m0 + 192);
    COMPUTE((const char*)Ks[1], (const char*)Vs[1], m0 + 64);
    if (t + 2 < NT){
      if (t + 3 < NT) WAITV4(); else WAITV0();
      WRITEA(0);
    }
    BARRIER();
  }

  // epilogue
  if (l31 == 0){
    #pragma unroll
    for (int e = 0; e < 16; ++e)
      lred[w][(e & 3) + 8 * (e >> 2) + 4 * hi] = lacc[e];
  }
  asm volatile("s_waitcnt lgkmcnt(0)" ::: "memory");
  f32x4 lv[4];
  #pragma unroll
  for (int g = 0; g < 4; ++g) lv[g] = *(const f32x4*)&lred[w][8 * g + 4 * hi];

  const size_t obase = (size_t)(b * NSEQ + q0 + w * 32) * SPD + h * DH_ + l31;
  #pragma unroll
  for (int e = 0; e < 16; ++e){
    const float linv = __builtin_amdgcn_rcpf(lv[e >> 2][e & 3]);
    const float ov0 = o[0][e] * linv;
    const float ov1 = o[1][e] * linv;
    float ss = ov0 * ov0 + ov1 * ov1;
    #pragma unroll
    for (int off = 16; off; off >>= 1) ss += __shfl_xor(ss, off, 64);
    const float nrm = sqrtf(ss);
    const float e2 = exp2f(SQRTK * nrm * LOG2E);
    const float einv = __builtin_amdgcn_rcpf(e2);
    const float fac = (e2 - einv) * 0.5f * __builtin_amdgcn_rcpf(SQRTK * fmaxf(nrm, 1e-9f));
    const int crow = (e & 3) + 8 * (e >> 2) + 4 * hi;
    catb[obase + (size_t)crow * SPD]      = f2bf(fac * ov0);
    catb[obase + (size_t)crow * SPD + 32] = f2bf(fac * ov1);
  }
#undef LOADA
#undef LOADB
#undef WRITEA
#undef WRITEB
#undef BARRIER
#undef WAITV4
#undef WAITV0
}

// ---------------- t' per row (wave-per-row, vectorized) ----------------
__global__ __launch_bounds__(256) void tp_kernel(const short* __restrict__ catb,
                                                 float* __restrict__ tps){
  const int lane = threadIdx.x & 63;
  const int row = blockIdx.x * 4 + (threadIdx.x >> 6);
  union { bf16x8 v; short e[8]; } u;
  u.v = *(const bf16x8*)(catb + (size_t)row * SPD + lane * 8);
  float s = 0.f;
  #pragma unroll
  for (int j = 0; j < 8; ++j){ const float f = bf2f(u.e[j]); s += f * f; }
  #pragma unroll
  for (int m = 1; m <= 32; m <<= 1) s += __shfl_xor(s, m, 64);
  if (lane == 0) tps[row] = sqrtf(fmaxf(INVK + s, 1e-9f));
}

// ---------------- final t_o per row (wave-per-row, coalesced) ----------------
__global__ __launch_bounds__(256) void fin_kernel(float* __restrict__ out){
  const int lane = threadIdx.x & 63;
  const int row = blockIdx.x * 4 + (threadIdx.x >> 6);
  const float* rp = out + (size_t)row * KDIM + 1;
  float s = 0.f;
  #pragma unroll
  for (int j = 0; j < 8; ++j){ const float f = rp[j * 64 + lane]; s += f * f; }
  #pragma unroll
  for (int m = 1; m <= 32; m <<= 1) s += __shfl_xor(s, m, 64);
  if (lane == 0) out[(size_t)row * KDIM] = sqrtf(fmaxf(INVK + s, 1e-9f));
}

extern "C" void kernel_launch(void* const* d_in, const int* in_sizes, int n_in,
                              void* d_out, int out_size, void* d_ws, size_t ws_size,
                              hipStream_t stream)
{
  (void)in_sizes; (void)n_in; (void)out_size; (void)ws_size;
  const float* x  = (const float*)d_in[0];
  const float* Wq = (const float*)d_in[1];
  const float* bq = (const float*)d_in[2];
  const float* Wk = (const float*)d_in[3];
  const float* bk = (const float*)d_in[4];
  const float* Wv = (const float*)d_in[5];
  const float* bv = (const float*)d_in[6];
  const float* Wo = (const float*)d_in[7];
  const float* bo = (const float*)d_in[8];
  float* out = (float*)d_out;

  char* p = (char*)d_ws;
  short* xs   = (short*)p; p += (size_t)ROWS * SPD * 2;
  short* WT   = (short*)p; p += (size_t)4 * SPD * SPD * 2;
  short* qb   = (short*)p; p += (size_t)ROWS * SPD * 2;
  short* kb   = (short*)p; p += (size_t)ROWS * SPD * 2;
  short* vb   = (short*)p; p += (size_t)ROWS * SPD * 2;
  short* vtT  = (short*)p; p += (size_t)ROWS * SPD * 2;
  float* tq   = (float*)p; p += (size_t)ROWS * 4;
  unsigned* tkpk = (unsigned*)p; p += (size_t)ROWS * 4;
  short* catb = (short*)p; p += (size_t)ROWS * SPD * 2;
  float* tps  = (float*)p; p += (size_t)ROWS * 4;

  conv_kernel<<<8192 + 4096, 256, 0, stream>>>(x, Wq, Wk, Wv, Wo, xs, WT);
  gemm_kernel<true, 128><<<dim3(64, 4, 3), 256, 0, stream>>>(
      xs, WT, 0, 1, 2, bq, bk, bv, Wq, Wk, Wv, x, (long)KDIM,
      qb, kb, vb, SPD, 0);
  postqkv_kernel<<<1024, 256, 0, stream>>>(qb, kb, vb, tq, tkpk, vtT);
  attn_kernel<<<512, 256, 0, stream>>>(qb, kb, vtT, tq, tkpk, catb);
  tp_kernel<<<ROWS / 4, 256, 0, stream>>>(catb, tps);
  gemm_kernel<false, 64><<<dim3(128, 4, 1), 256, 0, stream>>>(
      catb, WT, 3, 3, 3, bo, bo, bo, Wo, Wo, Wo, tps, 1L,
      out, out, out, KDIM, 1);
  fin_kernel<<<ROWS / 4, 256, 0, stream>>>(out);
}